// Round 2
// baseline (21630.106 us; speedup 1.0000x reference)
//
#include <hip/hip_runtime.h>

#define B_ 256
#define S_ 128
#define D_ 2
#define H_ 512
#define NB 256
#define NT 512

__device__ __forceinline__ float sigm(float x){ return 1.f/(1.f+__expf(-x)); }
__device__ __forceinline__ float tanh_(float x){ return 1.f - 2.f/(__expf(2.f*x)+1.f); }

// ---------------------------------------------------------------------------
// Grid-wide barrier (generation counting). All 256 blocks co-resident:
// grid=256, 64KB LDS -> >=1 block/CU capacity on 256 CUs.
// ---------------------------------------------------------------------------
__device__ __forceinline__ void grid_barrier(unsigned* bar) {
    __syncthreads();
    if (threadIdx.x == 0) {
        __threadfence();   // release: flush our stores (L2 wb) before arrive
        unsigned g = __hip_atomic_load(&bar[1], __ATOMIC_RELAXED, __HIP_MEMORY_SCOPE_AGENT);
        unsigned a = __hip_atomic_fetch_add(&bar[0], 1u, __ATOMIC_ACQ_REL, __HIP_MEMORY_SCOPE_AGENT);
        if (a == NB - 1u) {
            __hip_atomic_store(&bar[0], 0u, __ATOMIC_RELAXED, __HIP_MEMORY_SCOPE_AGENT);
            __hip_atomic_store(&bar[1], g + 1u, __ATOMIC_RELEASE, __HIP_MEMORY_SCOPE_AGENT);
        } else {
            while (__hip_atomic_load(&bar[1], __ATOMIC_RELAXED, __HIP_MEMORY_SCOPE_AGENT) == g)
                __builtin_amdgcn_s_sleep(2);
            __threadfence();   // acquire: invalidate L1/L2 before reading others' data
        }
    }
    __syncthreads();
}

// ---------------------------------------------------------------------------
// prep: dxw[j] = dec_bih[j]+dec_bhh[j] - sum_k dec_Wih[j][k]   (x == -1 const)
//       ebias[j] = enc_bih[j]+enc_bhh[j]
// ---------------------------------------------------------------------------
__global__ __launch_bounds__(256) void prep_kernel(
    const float* __restrict__ dWih, const float* __restrict__ dbih,
    const float* __restrict__ dbhh, const float* __restrict__ ebih,
    const float* __restrict__ ebhh, float* __restrict__ dxw,
    float* __restrict__ ebias)
{
    int j = blockIdx.x * 256 + threadIdx.x;   // 0..2047
    const float* row = dWih + (size_t)j * H_;
    float s = 0.f;
    for (int k = 0; k < H_; k++) s += row[k];
    dxw[j]   = dbih[j] + dbhh[j] - s;
    ebias[j] = ebih[j] + ebhh[j];
}

// ---------------------------------------------------------------------------
// Persistent encoder: 256 blocks x 512 thr. Block (bt,jt): b-tile 32, 16
// hidden units (x4 gates = 64 weight rows). Each thread keeps 64 floats of
// eWhh in VGPRs (its row wrow, k-slice wv*64..+64). K split across 8 waves;
// cross-wave reduce via XOR-swizzled LDS partials; gates in finalize.
// ---------------------------------------------------------------------------
__global__ __launch_bounds__(NT, 2) void enc_kernel(
    const float* __restrict__ x, const float* __restrict__ eWih,
    const float* __restrict__ eWhh, const float* __restrict__ ebias,
    float* enc_hs, float* c_fin, unsigned* bar)
{
    extern __shared__ float smem[];
    float (*Hs)[H_]    = (float (*)[H_])smem;             // [16][512] 32KB
    float (*Pl)[8][64] = (float (*)[8][64])(smem + 16*H_);// [16][8][64] 32KB

    const int tid = threadIdx.x;
    const int wv = tid >> 6, ln = tid & 63;
    const int bt = blockIdx.x >> 5, jt = blockIdx.x & 31;
    const int b0 = bt * 32, hu0 = jt * 16;
    const int lg = ln >> 4, lhu = ln & 15;
    const int wrow = lg * H_ + hu0 + lhu;

    float w[64];
    {
        const float4* wp = (const float4*)(eWhh + (size_t)wrow * H_ + wv * 64);
#pragma unroll
        for (int i = 0; i < 16; i++) {
            float4 t4 = wp[i];
            w[4*i+0]=t4.x; w[4*i+1]=t4.y; w[4*i+2]=t4.z; w[4*i+3]=t4.w;
        }
    }
    const int fb = tid >> 4, fh = tid & 15;     // finalize roles (tid<256)
    const int fhu = hu0 + fh;
    float eb4[4] = {0,0,0,0}, wi0[4] = {0,0,0,0}, wi1[4] = {0,0,0,0};
    if (tid < 256) {
#pragma unroll
        for (int g = 0; g < 4; g++) {
            eb4[g] = ebias[g*H_ + fhu];
            wi0[g] = eWih[(size_t)(g*H_ + fhu)*D_ + 0];
            wi1[g] = eWih[(size_t)(g*H_ + fhu)*D_ + 1];
        }
    }
    float creg0 = 0.f, creg1 = 0.f;

    for (int t = 0; t < S_; t++) {
        const float* hsrc = enc_hs + (size_t)(t-1) * H_;   // + b*S*H, valid t>0
#pragma unroll 1
        for (int bc = 0; bc < 2; bc++) {
            __syncthreads();
            {   // stage 16 rows of h_{t-1}
                int r = tid >> 5, c0 = (tid & 31) * 4;
                int b = b0 + bc*16 + r;
#pragma unroll
                for (int i = 0; i < 4; i++) {
                    float4 v4;
                    if (t == 0) v4 = make_float4(0.f,0.f,0.f,0.f);
                    else v4 = *(const float4*)(hsrc + (size_t)b * (S_*H_) + c0 + i*128);
                    *(float4*)&Hs[r][c0 + i*128] = v4;
                }
            }
            __syncthreads();
#pragma unroll 2
            for (int b8 = 0; b8 < 16; b8++) {
                const float4* hp = (const float4*)&Hs[b8][wv * 64];  // wave-uniform
                float acc = 0.f;
#pragma unroll
                for (int i = 0; i < 16; i++) {
                    float4 h4 = hp[i];
                    acc += h4.x*w[4*i] + h4.y*w[4*i+1] + h4.z*w[4*i+2] + h4.w*w[4*i+3];
                }
                Pl[b8][wv][ln ^ ((b8 & 15) << 2)] = acc;   // swizzle: conflict-free read
            }
            __syncthreads();
            if (tid < 256) {
                float z4[4];
#pragma unroll
                for (int g = 0; g < 4; g++) {
                    float s = 0.f;
#pragma unroll
                    for (int w8 = 0; w8 < 8; w8++)
                        s += Pl[fb][w8][(g*16 + fh) ^ ((fb & 15) << 2)];
                    z4[g] = s + eb4[g];
                }
                int b = b0 + bc*16 + fb;
                float x0 = x[(size_t)(b*S_ + t)*D_ + 0];
                float x1 = x[(size_t)(b*S_ + t)*D_ + 1];
                float zi = z4[0] + x0*wi0[0] + x1*wi1[0];
                float zf = z4[1] + x0*wi0[1] + x1*wi1[1];
                float zg = z4[2] + x0*wi0[2] + x1*wi1[2];
                float zo = z4[3] + x0*wi0[3] + x1*wi1[3];
                float cold = bc ? creg1 : creg0;
                float cn = sigm(zf)*cold + sigm(zi)*tanh_(zg);
                float hn = sigm(zo)*tanh_(cn);
                if (bc) creg1 = cn; else creg0 = cn;
                enc_hs[((size_t)b*S_ + t)*H_ + fhu] = hn;
            }
        }
        if (t < S_-1) grid_barrier(bar);
    }
    if (tid < 256) {
        c_fin[(size_t)(b0 + fb)*H_ + fhu]      = creg0;
        c_fin[(size_t)(b0 + 16 + fb)*H_ + fhu] = creg1;
    }
}

// ---------------------------------------------------------------------------
// Generic fp32 GEMM:  C[m][n] = sum_k A[m][k]*Bm[n][k] + bias[n]
// ---------------------------------------------------------------------------
template<int BM, int BN, int TM, int TN>
__global__ __launch_bounds__((BM/TM)*(BN/TN)) void gemm_bias(
    const float* __restrict__ A, const float* __restrict__ Bm,
    const float* __restrict__ bias, float* __restrict__ C,
    int M, int N, int K)
{
    constexpr int BK = 32;
    constexpr int TH = (BM / TM) * (BN / TN);
    constexpr int AL = BM * BK / TH;
    constexpr int BL = BN * BK / TH;
    constexpr int RP = TH / BK;
    __shared__ float As[BK][BM + 4];
    __shared__ float Bs[BK][BN + 4];
    const int tid = threadIdx.x;
    const int tn = tid % (BN / TN);
    const int tm = tid / (BN / TN);
    const int m0 = blockIdx.x * BM, n0 = blockIdx.y * BN;
    const int lk = tid % BK, lr = tid / BK;

    float acc[TM][TN];
#pragma unroll
    for (int i = 0; i < TM; i++)
#pragma unroll
        for (int j = 0; j < TN; j++) acc[i][j] = 0.f;

    float areg[AL], breg[BL];
#pragma unroll
    for (int i = 0; i < AL; i++) areg[i] = A[(size_t)(m0 + lr + i * RP) * K + lk];
#pragma unroll
    for (int i = 0; i < BL; i++) breg[i] = Bm[(size_t)(n0 + lr + i * RP) * K + lk];

    const int NC = K / BK;
    for (int c = 0; c < NC; c++) {
        __syncthreads();
#pragma unroll
        for (int i = 0; i < AL; i++) As[lk][lr + i * RP] = areg[i];
#pragma unroll
        for (int i = 0; i < BL; i++) Bs[lk][lr + i * RP] = breg[i];
        __syncthreads();
        if (c + 1 < NC) {
            int k0 = (c + 1) * BK;
#pragma unroll
            for (int i = 0; i < AL; i++) areg[i] = A[(size_t)(m0 + lr + i * RP) * K + k0 + lk];
#pragma unroll
            for (int i = 0; i < BL; i++) breg[i] = Bm[(size_t)(n0 + lr + i * RP) * K + k0 + lk];
        }
#pragma unroll
        for (int k = 0; k < BK; k++) {
            float av[TM], bvv[TN];
#pragma unroll
            for (int i = 0; i < TM; i++) av[i] = As[k][tm * TM + i];
#pragma unroll
            for (int j = 0; j < TN; j++) bvv[j] = Bs[k][tn * TN + j];
#pragma unroll
            for (int i = 0; i < TM; i++)
#pragma unroll
                for (int j = 0; j < TN; j++) acc[i][j] += av[i] * bvv[j];
        }
    }
#pragma unroll
    for (int i = 0; i < TM; i++) {
        int m = m0 + tm * TM + i;
#pragma unroll
        for (int j = 0; j < TN; j++) {
            int n = n0 + tn * TN + j;
            C[(size_t)m * N + n] = acc[i][j] + bias[n];
        }
    }
}

// ---------------------------------------------------------------------------
// Persistent decoder: per step {LSTM | barrier | W2h | barrier | attn | barrier}
// dWhh slice (64f) and W2 slice (16f) VGPR-resident for the whole kernel.
// ---------------------------------------------------------------------------
__global__ __launch_bounds__(NT, 2) void dec_kernel(
    const float* __restrict__ dWhh, const float* __restrict__ dxw,
    const float* __restrict__ W2, const float* __restrict__ b2,
    const float* __restrict__ vv, const float* __restrict__ bv,
    const float* __restrict__ enc_hs, const float* __restrict__ W1e,
    const float* __restrict__ c_fin,
    float* h_dec, float* W2h, float* h_glim, float* out, unsigned* bar)
{
    extern __shared__ float smem[];
    float (*Hs)[H_]    = (float (*)[H_])smem;               // 32KB
    float (*Pl)[8][64] = (float (*)[8][64])(smem + 16*H_);  // 32KB (phase L)
    float (*P2)[8][17] = (float (*)[8][17])(smem + 16*H_);  // overlay (phase W2h)
    float* u   = smem;                                      // overlay (phase A)
    float* red = smem + 128;

    const int tid = threadIdx.x;
    const int wv = tid >> 6, ln = tid & 63;
    const int bt = blockIdx.x >> 5, jt = blockIdx.x & 31;
    const int b0 = bt * 32, hu0 = jt * 16;
    const int lg = ln >> 4, lhu = ln & 15;
    const int wrow = lg * H_ + hu0 + lhu;

    float w[64];
    {
        const float4* wp = (const float4*)(dWhh + (size_t)wrow * H_ + wv * 64);
#pragma unroll
        for (int i = 0; i < 16; i++) {
            float4 t4 = wp[i];
            w[4*i+0]=t4.x; w[4*i+1]=t4.y; w[4*i+2]=t4.z; w[4*i+3]=t4.w;
        }
    }
    const int n_ = hu0 + lhu;          // W2 output row owned by this lane
    const int kg = wv * 4 + lg;        // k-group (32 x 16)
    float w2r[16];
    {
        const float4* p = (const float4*)(W2 + (size_t)n_ * H_ + kg * 16);
#pragma unroll
        for (int i = 0; i < 4; i++) {
            float4 t4 = p[i];
            w2r[4*i+0]=t4.x; w2r[4*i+1]=t4.y; w2r[4*i+2]=t4.z; w2r[4*i+3]=t4.w;
        }
    }
    const float4 vr0 = *(const float4*)(vv + ln*8);
    const float4 vr1 = *(const float4*)(vv + ln*8 + 4);
    const float bvr = bv[0];

    const int fb = tid >> 4, fh = tid & 15;
    const int fhu = hu0 + fh;
    float db4[4] = {0,0,0,0}, b2f = 0.f;
    float creg0 = 0.f, creg1 = 0.f;
    if (tid < 256) {
#pragma unroll
        for (int g = 0; g < 4; g++) db4[g] = dxw[g*H_ + fhu];
        b2f = b2[fhu];
        creg0 = c_fin[(size_t)(b0 + fb)*H_ + fhu];
        creg1 = c_fin[(size_t)(b0 + 16 + fb)*H_ + fhu];
    }

    const int bA = blockIdx.x;  // phase-A batch index
    const float* w1b = W1e + (size_t)bA * S_ * H_;
    const float* ebA = enc_hs + (size_t)bA * S_ * H_;

    for (int t = 0; t < S_; t++) {
        // ================= phase L: LSTM =================
        const float* hsrc = (t == 0) ? (enc_hs + (size_t)(S_-1)*H_) : h_glim;
        const size_t hstr = (t == 0) ? (size_t)(S_*H_) : (size_t)H_;
#pragma unroll 1
        for (int bc = 0; bc < 2; bc++) {
            __syncthreads();
            {
                int r = tid >> 5, c0 = (tid & 31) * 4;
                int b = b0 + bc*16 + r;
#pragma unroll
                for (int i = 0; i < 4; i++)
                    *(float4*)&Hs[r][c0 + i*128] =
                        *(const float4*)(hsrc + (size_t)b * hstr + c0 + i*128);
            }
            __syncthreads();
#pragma unroll 2
            for (int b8 = 0; b8 < 16; b8++) {
                const float4* hp = (const float4*)&Hs[b8][wv * 64];
                float acc = 0.f;
#pragma unroll
                for (int i = 0; i < 16; i++) {
                    float4 h4 = hp[i];
                    acc += h4.x*w[4*i] + h4.y*w[4*i+1] + h4.z*w[4*i+2] + h4.w*w[4*i+3];
                }
                Pl[b8][wv][ln ^ ((b8 & 15) << 2)] = acc;
            }
            __syncthreads();
            if (tid < 256) {
                float z4[4];
#pragma unroll
                for (int g = 0; g < 4; g++) {
                    float s = 0.f;
#pragma unroll
                    for (int w8 = 0; w8 < 8; w8++)
                        s += Pl[fb][w8][(g*16 + fh) ^ ((fb & 15) << 2)];
                    z4[g] = s + db4[g];
                }
                int b = b0 + bc*16 + fb;
                float cold = bc ? creg1 : creg0;
                float cn = sigm(z4[1])*cold + sigm(z4[0])*tanh_(z4[2]);
                float hn = sigm(z4[3])*tanh_(cn);
                if (bc) creg1 = cn; else creg0 = cn;
                h_dec[(size_t)b*H_ + fhu] = hn;
            }
        }
        grid_barrier(bar);
        // ================= phase W2h =================
#pragma unroll 1
        for (int bc = 0; bc < 2; bc++) {
            __syncthreads();
            {
                int r = tid >> 5, c0 = (tid & 31) * 4;
                int b = b0 + bc*16 + r;
#pragma unroll
                for (int i = 0; i < 4; i++)
                    *(float4*)&Hs[r][c0 + i*128] =
                        *(const float4*)(h_dec + (size_t)b * H_ + c0 + i*128);
            }
            __syncthreads();
#pragma unroll 2
            for (int b8 = 0; b8 < 16; b8++) {
                const float4* hp = (const float4*)&Hs[b8][kg * 16];
                float p = 0.f;
#pragma unroll
                for (int i = 0; i < 4; i++) {
                    float4 h4 = hp[i];
                    p += h4.x*w2r[4*i] + h4.y*w2r[4*i+1] + h4.z*w2r[4*i+2] + h4.w*w2r[4*i+3];
                }
                p += __shfl_xor(p, 16);
                p += __shfl_xor(p, 32);
                if (lg == 0) P2[b8][wv][lhu] = p;
            }
            __syncthreads();
            if (tid < 256) {
                float s = 0.f;
#pragma unroll
                for (int w8 = 0; w8 < 8; w8++) s += P2[fb][w8][fh];
                W2h[(size_t)(b0 + bc*16 + fb)*H_ + hu0 + fh] = s + b2f;
            }
        }
        grid_barrier(bar);
        // ================= phase A: attention =================
        {
            float4 q0 = *(const float4*)(W2h + (size_t)bA*H_ + ln*8);
            float4 q1 = *(const float4*)(W2h + (size_t)bA*H_ + ln*8 + 4);
#pragma unroll 2
            for (int si = 0; si < 16; si++) {
                int s = wv*16 + si;
                const float4* rp = (const float4*)(w1b + (size_t)s*H_ + ln*8);
                float4 r0 = rp[0], r1 = rp[1];
                float sum = tanh_(r0.x+q0.x)*vr0.x + tanh_(r0.y+q0.y)*vr0.y
                          + tanh_(r0.z+q0.z)*vr0.z + tanh_(r0.w+q0.w)*vr0.w
                          + tanh_(r1.x+q1.x)*vr1.x + tanh_(r1.y+q1.y)*vr1.y
                          + tanh_(r1.z+q1.z)*vr1.z + tanh_(r1.w+q1.w)*vr1.w;
#pragma unroll
                for (int off = 32; off; off >>= 1) sum += __shfl_xor(sum, off);
                if (ln == 0) u[s] = sum + bvr;
            }
            __syncthreads();
            float e = 0.f;
            if (tid < 128) {
                float m = u[tid];
#pragma unroll
                for (int off = 32; off; off >>= 1) m = fmaxf(m, __shfl_xor(m, off));
                if (ln == 0) red[tid >> 6] = m;
            }
            __syncthreads();
            if (tid < 128) {
                float mx = fmaxf(red[0], red[1]);
                e = __expf(u[tid] - mx);
                float ss = e;
#pragma unroll
                for (int off = 32; off; off >>= 1) ss += __shfl_xor(ss, off);
                if (ln == 0) red[2 + (tid >> 6)] = ss;
            }
            __syncthreads();
            if (tid < 128) {
                float a = e / (red[2] + red[3]);
                u[tid] = a;
                out[(size_t)bA*S_*S_ + (size_t)t*S_ + tid] = a;
            }
            __syncthreads();
            float acc = 0.f;
#pragma unroll 4
            for (int s = 0; s < S_; s++) acc += u[s] * ebA[(size_t)s*H_ + tid];
            h_glim[(size_t)bA*H_ + tid] = acc;
        }
        if (t < S_-1) grid_barrier(bar);
    }
}

// ---------------------------------------------------------------------------
extern "C" void kernel_launch(void* const* d_in, const int* in_sizes, int n_in,
                              void* d_out, int out_size, void* d_ws, size_t ws_size,
                              hipStream_t stream)
{
    const float* x    = (const float*)d_in[0];
    const float* eWih = (const float*)d_in[1];
    const float* eWhh = (const float*)d_in[2];
    const float* ebih = (const float*)d_in[3];
    const float* ebhh = (const float*)d_in[4];
    const float* dWih = (const float*)d_in[5];
    const float* dWhh = (const float*)d_in[6];
    const float* dbih = (const float*)d_in[7];
    const float* dbhh = (const float*)d_in[8];
    const float* W1   = (const float*)d_in[9];
    const float* b1   = (const float*)d_in[10];
    const float* W2   = (const float*)d_in[11];
    const float* b2   = (const float*)d_in[12];
    const float* vv   = (const float*)d_in[13];
    const float* bv   = (const float*)d_in[14];
    float* out = (float*)d_out;

    float* ws      = (float*)d_ws;
    float* enc_hs  = ws;                                   // B*S*H
    float* W1e     = enc_hs + (size_t)B_ * S_ * H_;        // B*S*H
    float* h_dec   = W1e    + (size_t)B_ * S_ * H_;        // B*H
    float* W2h     = h_dec  + (size_t)B_ * H_;             // B*H
    float* h_glim  = W2h    + (size_t)B_ * H_;             // B*H
    float* c_fin   = h_glim + (size_t)B_ * H_;             // B*H
    float* dxw     = c_fin  + (size_t)B_ * H_;             // 2048
    float* ebias   = dxw    + 2048;                        // 2048
    unsigned* bar  = (unsigned*)(ebias + 2048);            // 2 u32

    hipMemsetAsync(bar, 0, 2 * sizeof(unsigned), stream);
    prep_kernel<<<8, 256, 0, stream>>>(dWih, dbih, dbhh, ebih, ebhh, dxw, ebias);

    enc_kernel<<<NB, NT, 64*1024, stream>>>(x, eWih, eWhh, ebias, enc_hs, c_fin, bar);

    gemm_bias<64, 64, 4, 4><<<dim3((B_*S_)/64, H_/64), 256, 0, stream>>>(
        enc_hs, W1, b1, W1e, B_*S_, H_, H_);

    dec_kernel<<<NB, NT, 64*1024, stream>>>(dWhh, dxw, W2, b2, vv, bv,
                                            enc_hs, W1e, c_fin,
                                            h_dec, W2h, h_glim, out, bar);
}

// Round 3
// 13351.767 us; speedup vs baseline: 1.6200x; 1.6200x over previous
//
#include <hip/hip_runtime.h>

#define B_ 256
#define S_ 128
#define D_ 2
#define H_ 512

__device__ __forceinline__ float sigm(float x){ return 1.f/(1.f+__expf(-x)); }
__device__ __forceinline__ float tanh_(float x){ return 1.f - 2.f/(__expf(2.f*x)+1.f); }

// ---------------------------------------------------------------------------
// prep: dxw[j] = dec_bih[j]+dec_bhh[j] - sum_k dec_Wih[j][k]  (dec input = -1)
//       ebias[j] = enc_bih[j]+enc_bhh[j];  W2T[k][j] = W2[j][k]
// ---------------------------------------------------------------------------
__global__ __launch_bounds__(256) void prep3(
    const float* __restrict__ dWih, const float* __restrict__ dbih,
    const float* __restrict__ dbhh, const float* __restrict__ ebih,
    const float* __restrict__ ebhh, const float* __restrict__ W2,
    float* __restrict__ dxw, float* __restrict__ ebias, float* __restrict__ W2T)
{
    int bx = blockIdx.x, tid = threadIdx.x;
    if (bx < 8) {
        int j = bx * 256 + tid;
        const float* row = dWih + (size_t)j * H_;
        float s = 0.f;
        for (int k = 0; k < H_; k++) s += row[k];
        dxw[j]   = dbih[j] + dbhh[j] - s;
        ebias[j] = ebih[j] + ebhh[j];
    } else {
        int i = (bx - 8) * 256 + tid;        // 0..262143
        int k = i >> 9, j = i & 511;
        W2T[(size_t)k * H_ + j] = W2[(size_t)j * H_ + k];
    }
}

// ---------------------------------------------------------------------------
// pack Whh into [jt 32][ks 8][i4 16][rw 64][c 4] so each thread's 64 weights
// are contiguous & lane-coalesced.  sel 0 = encoder, 1 = decoder.
// ---------------------------------------------------------------------------
__global__ __launch_bounds__(256) void pack_whh(
    const float* __restrict__ eW, const float* __restrict__ dW,
    float* __restrict__ pe, float* __restrict__ pd)
{
    size_t n = (size_t)blockIdx.x * 256 + threadIdx.x;   // 0..2097151
    int sel = (int)(n >> 20);
    int m = (int)(n & 1048575);
    int c = m & 3, rw = (m >> 2) & 63, i4 = (m >> 8) & 15;
    int ks = (m >> 12) & 7, jt = m >> 15;
    int g = rw >> 4, hu = rw & 15;
    size_t src = (size_t)(g * H_ + jt * 16 + hu) * H_ + ks * 64 + i4 * 4 + c;
    if (sel) pd[m] = dW[src]; else pe[m] = eW[src];
}

// ---------------------------------------------------------------------------
// LSTM step v3: grid 512 blocks (bt 0..15 x jt 0..31) x 512 thr.
// Thread (ks=tid>>6, rw=tid&63): row (g=rw>>4, hu=rw&15) of gate block jt,
// k-slice ks*64..+64 in VGPRs. h over scalar pipe (wave-uniform s_loads).
// Partials reduced via pad-20 LDS; gates fused in finalize (256 threads).
// ---------------------------------------------------------------------------
template<bool ENC>
__global__ __launch_bounds__(512) void lstm_step3(
    const float* __restrict__ Wsrc, int packed,
    const float* __restrict__ h_in, long hstr, int hzero,
    float* __restrict__ c_st, int czero,
    const float* __restrict__ xbias,
    const float* __restrict__ Wih, const float* __restrict__ xt,
    float* __restrict__ h_out, long hostr)
{
    __shared__ float P[8][64][20];   // pad 20: 4-aligned, 8-way spread
    const int tid = threadIdx.x;
    const int rw = tid & 63;
    const int ks = __builtin_amdgcn_readfirstlane(tid >> 6);
    const int bx = blockIdx.x;
    const int bt = bx & 15, jt = bx >> 4;
    const int b0 = bt * 16;
    const int g = rw >> 4, hu = rw & 15;

    float w[64];
    if (packed) {
        const float4* wp = (const float4*)Wsrc + ((size_t)(jt * 8 + ks) * 16) * 64 + rw;
#pragma unroll
        for (int i = 0; i < 16; i++) {
            float4 t4 = wp[(size_t)i * 64];
            w[4*i+0]=t4.x; w[4*i+1]=t4.y; w[4*i+2]=t4.z; w[4*i+3]=t4.w;
        }
    } else {
        const float4* wp = (const float4*)(Wsrc + (size_t)(g * H_ + jt * 16 + hu) * H_ + ks * 64);
#pragma unroll
        for (int i = 0; i < 16; i++) {
            float4 t4 = wp[i];
            w[4*i+0]=t4.x; w[4*i+1]=t4.y; w[4*i+2]=t4.z; w[4*i+3]=t4.w;
        }
    }

    float acc[16];
#pragma unroll
    for (int b = 0; b < 16; b++) acc[b] = 0.f;
    if (!hzero) {
#pragma unroll
        for (int b = 0; b < 16; b++) {
            const float* hb = h_in + (size_t)(b0 + b) * hstr + ks * 64;  // uniform
            float s = 0.f;
#pragma unroll
            for (int i = 0; i < 64; i++) s += hb[i] * w[i];
            acc[b] = s;
        }
    }
#pragma unroll
    for (int b4 = 0; b4 < 4; b4++)
        *(float4*)&P[ks][rw][b4 * 4] =
            make_float4(acc[b4*4], acc[b4*4+1], acc[b4*4+2], acc[b4*4+3]);
    __syncthreads();

    if (tid < 256) {
        int b = tid & 15, h2 = tid >> 4;
        float z[4];
#pragma unroll
        for (int gg = 0; gg < 4; gg++) {
            int row = gg * 16 + h2;
            float s = 0.f;
#pragma unroll
            for (int k8 = 0; k8 < 8; k8++) s += P[k8][row][b];
            z[gg] = s + xbias[gg * H_ + jt * 16 + h2];
        }
        int bb = b0 + b, hj = jt * 16 + h2;
        if constexpr (ENC) {
            float x0 = xt[(size_t)bb * (S_ * D_) + 0];
            float x1 = xt[(size_t)bb * (S_ * D_) + 1];
#pragma unroll
            for (int gg = 0; gg < 4; gg++)
                z[gg] += x0 * Wih[(size_t)(gg * H_ + hj) * D_ + 0]
                       + x1 * Wih[(size_t)(gg * H_ + hj) * D_ + 1];
        }
        float cold = czero ? 0.f : c_st[(size_t)bb * H_ + hj];
        float cn = sigm(z[1]) * cold + sigm(z[0]) * tanh_(z[2]);
        float hn = sigm(z[3]) * tanh_(cn);
        c_st[(size_t)bb * H_ + hj] = cn;
        h_out[(size_t)bb * hostr + hj] = hn;
    }
}

// ---------------------------------------------------------------------------
// fp32 GEMM for W1e: C[m][n] = sum_k A[m][k]*Bm[n][k] + bias[n]
// ---------------------------------------------------------------------------
template<int BM, int BN, int TM, int TN>
__global__ __launch_bounds__((BM/TM)*(BN/TN)) void gemm_bias(
    const float* __restrict__ A, const float* __restrict__ Bm,
    const float* __restrict__ bias, float* __restrict__ C,
    int M, int N, int K)
{
    constexpr int BK = 32;
    constexpr int TH = (BM / TM) * (BN / TN);
    constexpr int AL = BM * BK / TH;
    constexpr int BL = BN * BK / TH;
    constexpr int RP = TH / BK;
    __shared__ float As[BK][BM + 4];
    __shared__ float Bs[BK][BN + 4];
    const int tid = threadIdx.x;
    const int tn = tid % (BN / TN);
    const int tm = tid / (BN / TN);
    const int m0 = blockIdx.x * BM, n0 = blockIdx.y * BN;
    const int lk = tid % BK, lr = tid / BK;

    float acc[TM][TN];
#pragma unroll
    for (int i = 0; i < TM; i++)
#pragma unroll
        for (int j = 0; j < TN; j++) acc[i][j] = 0.f;

    float areg[AL], breg[BL];
#pragma unroll
    for (int i = 0; i < AL; i++) areg[i] = A[(size_t)(m0 + lr + i * RP) * K + lk];
#pragma unroll
    for (int i = 0; i < BL; i++) breg[i] = Bm[(size_t)(n0 + lr + i * RP) * K + lk];

    const int NC = K / BK;
    for (int c = 0; c < NC; c++) {
        __syncthreads();
#pragma unroll
        for (int i = 0; i < AL; i++) As[lk][lr + i * RP] = areg[i];
#pragma unroll
        for (int i = 0; i < BL; i++) Bs[lk][lr + i * RP] = breg[i];
        __syncthreads();
        if (c + 1 < NC) {
            int k0 = (c + 1) * BK;
#pragma unroll
            for (int i = 0; i < AL; i++) areg[i] = A[(size_t)(m0 + lr + i * RP) * K + k0 + lk];
#pragma unroll
            for (int i = 0; i < BL; i++) breg[i] = Bm[(size_t)(n0 + lr + i * RP) * K + k0 + lk];
        }
#pragma unroll
        for (int k = 0; k < BK; k++) {
            float av[TM], bvv[TN];
#pragma unroll
            for (int i = 0; i < TM; i++) av[i] = As[k][tm * TM + i];
#pragma unroll
            for (int j = 0; j < TN; j++) bvv[j] = Bs[k][tn * TN + j];
#pragma unroll
            for (int i = 0; i < TM; i++)
#pragma unroll
                for (int j = 0; j < TN; j++) acc[i][j] += av[i] * bvv[j];
        }
    }
#pragma unroll
    for (int i = 0; i < TM; i++) {
        int m = m0 + tm * TM + i;
#pragma unroll
        for (int j = 0; j < TN; j++) {
            int n = n0 + tn * TN + j;
            C[(size_t)m * N + n] = acc[i][j] + bias[n];
        }
    }
}

// ---------------------------------------------------------------------------
// Fused W2h + attention: 256 blocks (one per batch) x 512 thr.
//  W2h[j] = sum_k W2T[k][j]*h_dec[b][k] + b2[j]      (k-split x4, LDS reduce)
//  u[s]   = sum_k tanh(W1e[b,s,k]+W2h[k])*v[k] + bv
//  a = softmax(u); out[b][t][:] = a; h_glim[b] = a @ enc_hs[b]
// ---------------------------------------------------------------------------
__global__ __launch_bounds__(512) void attn_fused(
    const float* __restrict__ W2T, const float* __restrict__ b2,
    const float* __restrict__ vv, const float* __restrict__ bv,
    const float* __restrict__ h_dec, const float* __restrict__ W1e,
    const float* __restrict__ enc_hs, float* __restrict__ out,
    float* __restrict__ h_glim, int t)
{
    __shared__ float hs[H_];
    __shared__ float qq[H_];
    __shared__ float pw[4][H_];
    __shared__ float ua[S_];
    __shared__ float red[8];
    const int tid = threadIdx.x;
    const int b = blockIdx.x;
    const int ln = tid & 63, wv = tid >> 6;

    if (tid < 128)
        *(float4*)&hs[tid * 4] = *(const float4*)&h_dec[(size_t)b * H_ + tid * 4];
    __syncthreads();

    {   // W2h partials
        const int j4 = tid & 127, kh = tid >> 7;   // kh 0..3
        float4 a4 = make_float4(0.f, 0.f, 0.f, 0.f);
        const float4* wp = (const float4*)W2T + j4;
        int kbeg = kh * 128;
#pragma unroll 4
        for (int k = kbeg; k < kbeg + 128; k++) {
            float4 w4 = wp[(size_t)k * 128];
            float hk = hs[k];
            a4.x += w4.x * hk; a4.y += w4.y * hk;
            a4.z += w4.z * hk; a4.w += w4.w * hk;
        }
        *(float4*)&pw[kh][j4 * 4] = a4;
    }
    __syncthreads();
    qq[tid] = pw[0][tid] + pw[1][tid] + pw[2][tid] + pw[3][tid] + b2[tid];
    __syncthreads();

    // u pass
    float4 q0 = *(float4*)&qq[ln * 8], q1 = *(float4*)&qq[ln * 8 + 4];
    float4 v0 = *(const float4*)(vv + ln * 8), v1 = *(const float4*)(vv + ln * 8 + 4);
    const float bvr = bv[0];
    const float* w1b = W1e + (size_t)b * S_ * H_;
#pragma unroll 2
    for (int si = 0; si < 16; si++) {
        int s = wv * 16 + si;
        const float4* rp = (const float4*)(w1b + (size_t)s * H_ + ln * 8);
        float4 r0 = rp[0], r1 = rp[1];
        float sum = tanh_(r0.x + q0.x) * v0.x + tanh_(r0.y + q0.y) * v0.y
                  + tanh_(r0.z + q0.z) * v0.z + tanh_(r0.w + q0.w) * v0.w
                  + tanh_(r1.x + q1.x) * v1.x + tanh_(r1.y + q1.y) * v1.y
                  + tanh_(r1.z + q1.z) * v1.z + tanh_(r1.w + q1.w) * v1.w;
#pragma unroll
        for (int off = 32; off; off >>= 1) sum += __shfl_xor(sum, off);
        if (ln == 0) ua[s] = sum + bvr;
    }
    __syncthreads();

    // softmax over ua[0..127]
    float e = 0.f;
    if (tid < 128) {
        float m = ua[tid];
#pragma unroll
        for (int off = 32; off; off >>= 1) m = fmaxf(m, __shfl_xor(m, off));
        if (ln == 0) red[tid >> 6] = m;
    }
    __syncthreads();
    if (tid < 128) {
        float mx = fmaxf(red[0], red[1]);
        e = __expf(ua[tid] - mx);
        float ss = e;
#pragma unroll
        for (int off = 32; off; off >>= 1) ss += __shfl_xor(ss, off);
        if (ln == 0) red[2 + (tid >> 6)] = ss;
    }
    __syncthreads();
    if (tid < 128) {
        float a = e / (red[2] + red[3]);
        ua[tid] = a;
        out[(size_t)b * S_ * S_ + (size_t)t * S_ + tid] = a;
    }
    __syncthreads();

    // glimpse
    const float* eb = enc_hs + (size_t)b * S_ * H_;
    float ga = 0.f;
#pragma unroll 4
    for (int s = 0; s < S_; s++) ga += ua[s] * eb[(size_t)s * H_ + tid];
    h_glim[(size_t)b * H_ + tid] = ga;
}

// ---------------------------------------------------------------------------
extern "C" void kernel_launch(void* const* d_in, const int* in_sizes, int n_in,
                              void* d_out, int out_size, void* d_ws, size_t ws_size,
                              hipStream_t stream)
{
    const float* x    = (const float*)d_in[0];
    const float* eWih = (const float*)d_in[1];
    const float* eWhh = (const float*)d_in[2];
    const float* ebih = (const float*)d_in[3];
    const float* ebhh = (const float*)d_in[4];
    const float* dWih = (const float*)d_in[5];
    const float* dWhh = (const float*)d_in[6];
    const float* dbih = (const float*)d_in[7];
    const float* dbhh = (const float*)d_in[8];
    const float* W1   = (const float*)d_in[9];
    const float* b1   = (const float*)d_in[10];
    const float* W2   = (const float*)d_in[11];
    const float* b2   = (const float*)d_in[12];
    const float* vv   = (const float*)d_in[13];
    const float* bv   = (const float*)d_in[14];
    float* out = (float*)d_out;

    float* ws     = (float*)d_ws;
    float* enc_hs = ws;                                    // 16777216
    float* W1e    = enc_hs + (size_t)B_ * S_ * H_;         // 16777216
    float* h_dec  = W1e    + (size_t)B_ * S_ * H_;         // 131072
    float* h_glim = h_dec  + (size_t)B_ * H_;              // 131072
    float* c_cur  = h_glim + (size_t)B_ * H_;              // 131072
    float* W2T    = c_cur  + (size_t)B_ * H_;              // 262144
    float* dxw    = W2T    + (size_t)H_ * H_;              // 2048
    float* ebias  = dxw    + 2048;                         // 2048
    float* wpk_e  = ebias  + 2048;                         // 1048576 (optional)
    float* wpk_d  = wpk_e  + 1048576;                      // 1048576 (optional)

    size_t base_f = (size_t)(wpk_e - ws);
    int packed = (ws_size >= (base_f + 2u * 1048576u) * sizeof(float)) ? 1 : 0;

    prep3<<<1032, 256, 0, stream>>>(dWih, dbih, dbhh, ebih, ebhh, W2,
                                    dxw, ebias, W2T);
    if (packed)
        pack_whh<<<8192, 256, 0, stream>>>(eWhh, dWhh, wpk_e, wpk_d);

    const float* We = packed ? wpk_e : eWhh;
    const float* Wd = packed ? wpk_d : dWhh;

    // ---- encoder ----
    for (int t = 0; t < S_; t++) {
        lstm_step3<true><<<512, 512, 0, stream>>>(
            We, packed,
            enc_hs + (size_t)(t - 1) * H_, (long)(S_ * H_), (t == 0) ? 1 : 0,
            c_cur, (t == 0) ? 1 : 0,
            ebias, eWih, x + (size_t)t * D_,
            enc_hs + (size_t)t * H_, (long)(S_ * H_));
    }

    // ---- W1e = enc_hs @ W1^T + b1 ----
    gemm_bias<64, 64, 4, 4><<<dim3((B_ * S_) / 64, H_ / 64), 256, 0, stream>>>(
        enc_hs, W1, b1, W1e, B_ * S_, H_, H_);

    // ---- decoder ----
    for (int t = 0; t < S_; t++) {
        const float* h_in = (t == 0) ? (enc_hs + (size_t)(S_ - 1) * H_) : h_glim;
        long hstr = (t == 0) ? (long)(S_ * H_) : (long)H_;
        lstm_step3<false><<<512, 512, 0, stream>>>(
            Wd, packed, h_in, hstr, 0,
            c_cur, 0, dxw, nullptr, nullptr,
            h_dec, (long)H_);
        attn_fused<<<B_, 512, 0, stream>>>(W2T, b2, vv, bv,
                                           h_dec, W1e, enc_hs, out, h_glim, t);
    }
}

// Round 4
// 12546.925 us; speedup vs baseline: 1.7239x; 1.0641x over previous
//
#include <hip/hip_runtime.h>

#define B_ 256
#define S_ 128
#define D_ 2
#define H_ 512
#define W2TP 528   // padded W2T row stride (floats): breaks 2KB L2 aliasing

__device__ __forceinline__ float sigm(float x){ return 1.f/(1.f+__expf(-x)); }
__device__ __forceinline__ float tanh_(float x){ return 1.f - 2.f/(__expf(2.f*x)+1.f); }

// ---------------------------------------------------------------------------
// prep: dxw[j] = dec_bih[j]+dec_bhh[j] - sum_k dec_Wih[j][k]  (dec input = -1)
//       ebias[j] = enc_bih[j]+enc_bhh[j];  W2Tp[k][j] = W2[j][k] (stride 528)
// ---------------------------------------------------------------------------
__global__ __launch_bounds__(256) void prep4(
    const float* __restrict__ dWih, const float* __restrict__ dbih,
    const float* __restrict__ dbhh, const float* __restrict__ ebih,
    const float* __restrict__ ebhh, const float* __restrict__ W2,
    float* __restrict__ dxw, float* __restrict__ ebias, float* __restrict__ W2Tp)
{
    int bx = blockIdx.x, tid = threadIdx.x;
    if (bx < 8) {
        int j = bx * 256 + tid;
        const float* row = dWih + (size_t)j * H_;
        float s = 0.f;
        for (int k = 0; k < H_; k++) s += row[k];
        dxw[j]   = dbih[j] + dbhh[j] - s;
        ebias[j] = ebih[j] + ebhh[j];
    } else {
        int i = (bx - 8) * 256 + tid;        // 0..262143
        int k = i >> 9, j = i & 511;
        W2Tp[(size_t)k * W2TP + j] = W2[(size_t)j * H_ + k];
    }
}

// ---------------------------------------------------------------------------
// pack Whh into [jt 32][ks 8][i4 16][rw 64][c 4]: each thread's 64 weights
// lane-coalesced.  n>=2^20 selects decoder.
// ---------------------------------------------------------------------------
__global__ __launch_bounds__(256) void pack_whh(
    const float* __restrict__ eW, const float* __restrict__ dW,
    float* __restrict__ pe, float* __restrict__ pd)
{
    size_t n = (size_t)blockIdx.x * 256 + threadIdx.x;   // 0..2097151
    int sel = (int)(n >> 20);
    int m = (int)(n & 1048575);
    int c = m & 3, rw = (m >> 2) & 63, i4 = (m >> 8) & 15;
    int ks = (m >> 12) & 7, jt = m >> 15;
    int g = rw >> 4, hu = rw & 15;
    size_t src = (size_t)(g * H_ + jt * 16 + hu) * H_ + ks * 64 + i4 * 4 + c;
    if (sel) pd[m] = dW[src]; else pe[m] = eW[src];
}

// ---------------------------------------------------------------------------
// LSTM step v4: grid 512 (bt 0..15 x jt 0..31) x 512 thr.
// Thread (ks=tid>>6, rw=tid&63): weight row (g=rw>>4, hu=rw&15) of block jt,
// k-slice ks*64..+64 in VGPRs (packed loads coalesced).  h staged in LDS,
// inner loop = wave-uniform broadcast ds_read_b128 + 4 FMA per 16B.
// Partials P[8][16][68] overlaid on Hs; gates fused in finalize.
// ---------------------------------------------------------------------------
template<bool ENC>
__global__ __launch_bounds__(512) void lstm_step4(
    const float* __restrict__ Wsrc, int packed,
    const float* __restrict__ h_in, long hstr, int hzero,
    float* __restrict__ c_st, int czero,
    const float* __restrict__ xbias,
    const float* __restrict__ Wih, const float* __restrict__ xt,
    float* __restrict__ h_out, long hostr)
{
    __shared__ float smem[8704];                    // 34.8KB: Hs / P overlay
    float (*Hs)[H_]     = (float (*)[H_])smem;      // [16][512]
    float (*P)[16][68]  = (float (*)[16][68])smem;  // [8][16][68]

    const int tid = threadIdx.x;
    const int rw = tid & 63;
    const int ks = tid >> 6;
    const int bx = blockIdx.x;
    const int bt = bx & 15, jt = bx >> 4;
    const int b0 = bt * 16;
    const int g = rw >> 4, hu = rw & 15;

    float w[64];
    if (packed) {
        const float4* wp = (const float4*)Wsrc + (size_t)(jt * 8 + ks) * 1024 + rw;
#pragma unroll
        for (int i = 0; i < 16; i++) {
            float4 t4 = wp[(size_t)i * 64];
            w[4*i+0]=t4.x; w[4*i+1]=t4.y; w[4*i+2]=t4.z; w[4*i+3]=t4.w;
        }
    } else {
        const float4* wp = (const float4*)(Wsrc + (size_t)(g * H_ + jt * 16 + hu) * H_ + ks * 64);
#pragma unroll
        for (int i = 0; i < 16; i++) {
            float4 t4 = wp[i];
            w[4*i+0]=t4.x; w[4*i+1]=t4.y; w[4*i+2]=t4.z; w[4*i+3]=t4.w;
        }
    }

    float acc[16];
#pragma unroll
    for (int b = 0; b < 16; b++) acc[b] = 0.f;

    if (!hzero) {
        {   // stage h rows b0..b0+15 into LDS
            int r = tid >> 5, c0 = (tid & 31) * 4;
            const float* hr = h_in + (size_t)(b0 + r) * hstr;
#pragma unroll
            for (int i = 0; i < 4; i++)
                *(float4*)&Hs[r][c0 + i * 128] = *(const float4*)(hr + c0 + i * 128);
        }
        __syncthreads();
#pragma unroll 2
        for (int b = 0; b < 16; b++) {
            const float4* hp = (const float4*)&Hs[b][ks * 64];   // wave-uniform
            float s = 0.f;
#pragma unroll
            for (int i = 0; i < 16; i++) {
                float4 h4 = hp[i];
                s += h4.x*w[4*i] + h4.y*w[4*i+1] + h4.z*w[4*i+2] + h4.w*w[4*i+3];
            }
            acc[b] = s;
        }
        __syncthreads();   // all Hs reads done before P overlay
    }

#pragma unroll
    for (int b = 0; b < 16; b++) P[ks][b][rw] = acc[b];
    __syncthreads();

    if (tid < 256) {
        int b = tid & 15, h2 = tid >> 4;
        float z[4];
#pragma unroll
        for (int gg = 0; gg < 4; gg++) {
            int row = gg * 16 + h2;
            float s = 0.f;
#pragma unroll
            for (int k8 = 0; k8 < 8; k8++) s += P[k8][b][row];
            z[gg] = s + xbias[gg * H_ + jt * 16 + h2];
        }
        int bb = b0 + b, hj = jt * 16 + h2;
        if constexpr (ENC) {
            float x0 = xt[(size_t)bb * (S_ * D_) + 0];
            float x1 = xt[(size_t)bb * (S_ * D_) + 1];
#pragma unroll
            for (int gg = 0; gg < 4; gg++)
                z[gg] += x0 * Wih[(size_t)(gg * H_ + hj) * D_ + 0]
                       + x1 * Wih[(size_t)(gg * H_ + hj) * D_ + 1];
        }
        float cold = czero ? 0.f : c_st[(size_t)bb * H_ + hj];
        float cn = sigm(z[1]) * cold + sigm(z[0]) * tanh_(z[2]);
        float hn = sigm(z[3]) * tanh_(cn);
        c_st[(size_t)bb * H_ + hj] = cn;
        h_out[(size_t)bb * hostr + hj] = hn;
    }
}

// ---------------------------------------------------------------------------
// W2h step: w2h[b][j] = b2[j] + sum_k W2Tp[k][j]*h_dec[b][k]
// grid 512 (bt 16 x jt 32) x 512 thr; block = 16 b x 16 j; per-block W2T
// read = 32KB (its own j-slice only).
// ---------------------------------------------------------------------------
__global__ __launch_bounds__(512) void w2h_step(
    const float* __restrict__ W2Tp, const float* __restrict__ b2,
    const float* __restrict__ h_dec, float* __restrict__ w2h)
{
    __shared__ float smem[8704];                    // Hs [16][512] / P2 [32][16][17]
    float (*Hs)[H_]    = (float (*)[H_])smem;
    float (*P2)[16][17] = (float (*)[16][17])smem;

    const int tid = threadIdx.x;
    const int ks = tid >> 6, rw = tid & 63;
    const int ksub = rw >> 4, j = rw & 15;
    const int bx = blockIdx.x;
    const int bt = bx & 15, jt = bx >> 4;
    const int b0 = bt * 16, j0 = jt * 16;

    {
        int r = tid >> 5, c0 = (tid & 31) * 4;
        const float* hr = h_dec + (size_t)(b0 + r) * H_;
#pragma unroll
        for (int i = 0; i < 4; i++)
            *(float4*)&Hs[r][c0 + i * 128] = *(const float4*)(hr + c0 + i * 128);
    }
    __syncthreads();

    const int kk = ks * 64 + ksub * 16;
    float w2r[16];
#pragma unroll
    for (int i = 0; i < 16; i++) w2r[i] = W2Tp[(size_t)(kk + i) * W2TP + j0 + j];

    float acc[16];
#pragma unroll
    for (int b = 0; b < 16; b++) {
        float s = 0.f;
#pragma unroll
        for (int i = 0; i < 16; i++) s += Hs[b][kk + i] * w2r[i];
        acc[b] = s;
    }
    __syncthreads();
#pragma unroll
    for (int b = 0; b < 16; b++) P2[ks * 4 + ksub][b][j] = acc[b];
    __syncthreads();

    if (tid < 256) {
        int b = tid & 15, jj = tid >> 4;
        float s = 0.f;
#pragma unroll
        for (int p = 0; p < 32; p++) s += P2[p][b][jj];
        w2h[(size_t)(b0 + b) * H_ + j0 + jj] = s + b2[j0 + jj];
    }
}

// ---------------------------------------------------------------------------
// fp32 GEMM for W1e: C[m][n] = sum_k A[m][k]*Bm[n][k] + bias[n]
// ---------------------------------------------------------------------------
template<int BM, int BN, int TM, int TN>
__global__ __launch_bounds__((BM/TM)*(BN/TN)) void gemm_bias(
    const float* __restrict__ A, const float* __restrict__ Bm,
    const float* __restrict__ bias, float* __restrict__ C,
    int M, int N, int K)
{
    constexpr int BK = 32;
    constexpr int TH = (BM / TM) * (BN / TN);
    constexpr int AL = BM * BK / TH;
    constexpr int BL = BN * BK / TH;
    constexpr int RP = TH / BK;
    __shared__ float As[BK][BM + 4];
    __shared__ float Bs[BK][BN + 4];
    const int tid = threadIdx.x;
    const int tn = tid % (BN / TN);
    const int tm = tid / (BN / TN);
    const int m0 = blockIdx.x * BM, n0 = blockIdx.y * BN;
    const int lk = tid % BK, lr = tid / BK;

    float acc[TM][TN];
#pragma unroll
    for (int i = 0; i < TM; i++)
#pragma unroll
        for (int j = 0; j < TN; j++) acc[i][j] = 0.f;

    float areg[AL], breg[BL];
#pragma unroll
    for (int i = 0; i < AL; i++) areg[i] = A[(size_t)(m0 + lr + i * RP) * K + lk];
#pragma unroll
    for (int i = 0; i < BL; i++) breg[i] = Bm[(size_t)(n0 + lr + i * RP) * K + lk];

    const int NC = K / BK;
    for (int c = 0; c < NC; c++) {
        __syncthreads();
#pragma unroll
        for (int i = 0; i < AL; i++) As[lk][lr + i * RP] = areg[i];
#pragma unroll
        for (int i = 0; i < BL; i++) Bs[lk][lr + i * RP] = breg[i];
        __syncthreads();
        if (c + 1 < NC) {
            int k0 = (c + 1) * BK;
#pragma unroll
            for (int i = 0; i < AL; i++) areg[i] = A[(size_t)(m0 + lr + i * RP) * K + k0 + lk];
#pragma unroll
            for (int i = 0; i < BL; i++) breg[i] = Bm[(size_t)(n0 + lr + i * RP) * K + k0 + lk];
        }
#pragma unroll
        for (int k = 0; k < BK; k++) {
            float av[TM], bvv[TN];
#pragma unroll
            for (int i = 0; i < TM; i++) av[i] = As[k][tm * TM + i];
#pragma unroll
            for (int j = 0; j < TN; j++) bvv[j] = Bs[k][tn * TN + j];
#pragma unroll
            for (int i = 0; i < TM; i++)
#pragma unroll
                for (int j = 0; j < TN; j++) acc[i][j] += av[i] * bvv[j];
        }
    }
#pragma unroll
    for (int i = 0; i < TM; i++) {
        int m = m0 + tm * TM + i;
#pragma unroll
        for (int j = 0; j < TN; j++) {
            int n = n0 + tn * TN + j;
            C[(size_t)m * N + n] = acc[i][j] + bias[n];
        }
    }
}

// ---------------------------------------------------------------------------
// Attention step (one block per batch b, 512 threads):
//  u[s] = sum_k tanh(W1e[b,s,k]+w2h[b,k])*v[k] + bv; a = softmax(u)
//  out[b][t][:] = a; h_glim[b] = a @ enc_hs[b]
// ---------------------------------------------------------------------------
__global__ __launch_bounds__(512) void attn_step(
    const float* __restrict__ w2h, const float* __restrict__ vv,
    const float* __restrict__ bv, const float* __restrict__ W1e,
    const float* __restrict__ enc_hs, float* __restrict__ out,
    float* __restrict__ h_glim, int t)
{
    __shared__ float ua[S_];
    __shared__ float red[8];
    const int tid = threadIdx.x;
    const int b = blockIdx.x;
    const int ln = tid & 63, wv = tid >> 6;

    float4 q0 = *(const float4*)(w2h + (size_t)b * H_ + ln * 8);
    float4 q1 = *(const float4*)(w2h + (size_t)b * H_ + ln * 8 + 4);
    float4 v0 = *(const float4*)(vv + ln * 8);
    float4 v1 = *(const float4*)(vv + ln * 8 + 4);
    const float bvr = bv[0];
    const float* w1b = W1e + (size_t)b * S_ * H_;
#pragma unroll 2
    for (int si = 0; si < 16; si++) {
        int s = wv * 16 + si;
        const float4* rp = (const float4*)(w1b + (size_t)s * H_ + ln * 8);
        float4 r0 = rp[0], r1 = rp[1];
        float sum = tanh_(r0.x + q0.x) * v0.x + tanh_(r0.y + q0.y) * v0.y
                  + tanh_(r0.z + q0.z) * v0.z + tanh_(r0.w + q0.w) * v0.w
                  + tanh_(r1.x + q1.x) * v1.x + tanh_(r1.y + q1.y) * v1.y
                  + tanh_(r1.z + q1.z) * v1.z + tanh_(r1.w + q1.w) * v1.w;
#pragma unroll
        for (int off = 32; off; off >>= 1) sum += __shfl_xor(sum, off);
        if (ln == 0) ua[s] = sum + bvr;
    }
    __syncthreads();

    float e = 0.f;
    if (tid < 128) {
        float m = ua[tid];
#pragma unroll
        for (int off = 32; off; off >>= 1) m = fmaxf(m, __shfl_xor(m, off));
        if (ln == 0) red[tid >> 6] = m;
    }
    __syncthreads();
    if (tid < 128) {
        float mx = fmaxf(red[0], red[1]);
        e = __expf(ua[tid] - mx);
        float ss = e;
#pragma unroll
        for (int off = 32; off; off >>= 1) ss += __shfl_xor(ss, off);
        if (ln == 0) red[2 + (tid >> 6)] = ss;
    }
    __syncthreads();
    if (tid < 128) {
        float a = e / (red[2] + red[3]);
        ua[tid] = a;
        out[(size_t)b * S_ * S_ + (size_t)t * S_ + tid] = a;
    }
    __syncthreads();

    const float* eb = enc_hs + (size_t)b * S_ * H_;
    float ga = 0.f;
#pragma unroll 4
    for (int s = 0; s < S_; s++) ga += ua[s] * eb[(size_t)s * H_ + tid];
    h_glim[(size_t)b * H_ + tid] = ga;
}

// ---------------------------------------------------------------------------
extern "C" void kernel_launch(void* const* d_in, const int* in_sizes, int n_in,
                              void* d_out, int out_size, void* d_ws, size_t ws_size,
                              hipStream_t stream)
{
    const float* x    = (const float*)d_in[0];
    const float* eWih = (const float*)d_in[1];
    const float* eWhh = (const float*)d_in[2];
    const float* ebih = (const float*)d_in[3];
    const float* ebhh = (const float*)d_in[4];
    const float* dWih = (const float*)d_in[5];
    const float* dWhh = (const float*)d_in[6];
    const float* dbih = (const float*)d_in[7];
    const float* dbhh = (const float*)d_in[8];
    const float* W1   = (const float*)d_in[9];
    const float* b1   = (const float*)d_in[10];
    const float* W2   = (const float*)d_in[11];
    const float* b2   = (const float*)d_in[12];
    const float* vv   = (const float*)d_in[13];
    const float* bv   = (const float*)d_in[14];
    float* out = (float*)d_out;

    float* ws     = (float*)d_ws;
    float* enc_hs = ws;                                    // 16777216
    float* W1e    = enc_hs + (size_t)B_ * S_ * H_;         // 16777216
    float* h_dec  = W1e    + (size_t)B_ * S_ * H_;         // 131072
    float* h_glim = h_dec  + (size_t)B_ * H_;              // 131072
    float* c_cur  = h_glim + (size_t)B_ * H_;              // 131072
    float* w2h    = c_cur  + (size_t)B_ * H_;              // 131072
    float* W2Tp   = w2h    + (size_t)B_ * H_;              // 512*528 = 270336
    float* dxw    = W2Tp   + (size_t)H_ * W2TP;            // 2048
    float* ebias  = dxw    + 2048;                         // 2048
    float* wpk_e  = ebias  + 2048;                         // 1048576 (optional)
    float* wpk_d  = wpk_e  + 1048576;                      // 1048576 (optional)

    size_t base_f = (size_t)(wpk_e - ws);
    int packed = (ws_size >= (base_f + 2097152u) * sizeof(float)) ? 1 : 0;

    prep4<<<1032, 256, 0, stream>>>(dWih, dbih, dbhh, ebih, ebhh, W2,
                                    dxw, ebias, W2Tp);
    if (packed)
        pack_whh<<<8192, 256, 0, stream>>>(eWhh, dWhh, wpk_e, wpk_d);

    const float* We = packed ? wpk_e : eWhh;
    const float* Wd = packed ? wpk_d : dWhh;

    // ---- encoder ----
    for (int t = 0; t < S_; t++) {
        lstm_step4<true><<<512, 512, 0, stream>>>(
            We, packed,
            enc_hs + (size_t)(t - 1) * H_, (long)(S_ * H_), (t == 0) ? 1 : 0,
            c_cur, (t == 0) ? 1 : 0,
            ebias, eWih, x + (size_t)t * D_,
            enc_hs + (size_t)t * H_, (long)(S_ * H_));
    }

    // ---- W1e = enc_hs @ W1^T + b1 ----
    gemm_bias<128, 128, 8, 8><<<dim3((B_ * S_) / 128, H_ / 128), 256, 0, stream>>>(
        enc_hs, W1, b1, W1e, B_ * S_, H_, H_);

    // ---- decoder ----
    for (int t = 0; t < S_; t++) {
        const float* h_in = (t == 0) ? (enc_hs + (size_t)(S_ - 1) * H_) : h_glim;
        long hstr = (t == 0) ? (long)(S_ * H_) : (long)H_;
        lstm_step4<false><<<512, 512, 0, stream>>>(
            Wd, packed, h_in, hstr, 0,
            c_cur, 0, dxw, nullptr, nullptr,
            h_dec, (long)H_);
        w2h_step<<<512, 512, 0, stream>>>(W2Tp, b2, h_dec, w2h);
        attn_step<<<B_, 512, 0, stream>>>(w2h, vv, bv, W1e, enc_hs, out, h_glim, t);
    }
}